// Round 8
// baseline (972.737 us; speedup 1.0000x reference)
//
#include <hip/hip_runtime.h>

#define B_ 256
#define L_ 2048
#define T_ 64
#define TS_ 66   // TRANS_SIZE
#define START_ 64
#define END_ 65
#define NB_ 16   // batches per block (one fwd wave)
#define LN2_ 0.69314718055994531f

typedef float f32x4 __attribute__((ext_vector_type(4)));
typedef short bf16x8 __attribute__((ext_vector_type(8)));
typedef int   i32x4 __attribute__((ext_vector_type(4)));

__device__ __forceinline__ int cvtpk(float lo, float hi) {
    int r; asm("v_cvt_pk_bf16_f32 %0, %1, %2" : "=v"(r) : "v"(lo), "v"(hi)); return r;
}
// v_permlane32_swap_b32: a' = [a_lo32 | b_lo32], b' = [a_hi32 | b_hi32]
__device__ __forceinline__ void pl32(int& a, int& b) {
    asm("v_permlane32_swap_b32 %0, %1" : "+v"(a), "+v"(b));
}
// v_permlane16_swap_b32: a' = [a_g0, b_g0, a_g2, b_g2], b' = [a_g1, b_g1, a_g3, b_g3]
__device__ __forceinline__ void pl16(int& a, int& b) {
    asm("v_permlane16_swap_b32 %0, %1" : "+v"(a), "+v"(b));
}
__device__ __forceinline__ bf16x8 mkfrag(int w0, int w1, int w2, int w3) {
    i32x4 t; t[0] = w0; t[1] = w1; t[2] = w2; t[3] = w3;
    return __builtin_bit_cast(bf16x8, t);
}

// grid = B_/NB_ blocks x 256 threads. Wave 0: MFMA forward chains, 16 batches.
// Waves 1-3: gold-path scores for the same batches (hidden under wave 0).
__global__ __launch_bounds__(256, 1) void crf_fused(
    const float* __restrict__ feat,   // RAW features
    const int* __restrict__ tags, const int* __restrict__ lengths,
    const float* __restrict__ trans, float* __restrict__ out)
{
    const int bb  = blockIdx.x * NB_;
    const int tid = threadIdx.x;
    const int wid = tid >> 6;
    const int l   = tid & 63;

    if (wid != 0) {
        // ---- gold-path ("real") scores, negated ----
        for (int bi = wid - 1; bi < NB_; bi += 3) {
            const int b = bb + bi;
            const int len = lengths[b];
            const int* tg = tags + (size_t)b * L_;
            const float* fb = feat + (size_t)b * (L_ * T_);
            float local = 0.f;
            for (int t = l; t < len; t += 64)
                local += fb[(size_t)t * T_ + tg[t]];
            for (int t = l; t + 1 < len; t += 64)
                local += trans[tg[t] * TS_ + tg[t + 1]];
            #pragma unroll
            for (int d = 32; d >= 1; d >>= 1) local += __shfl_xor(local, d, 64);
            if (l == 0) {
                local += trans[START_ * TS_ + tg[0]];
                local += trans[tg[len - 1] * TS_ + END_];
                atomicAdd(out, -local * (1.0f / (float)B_));
            }
        }
        return;
    }

    // ---------------- forward wave: 16 chains via MFMA ----------------
    const int n = l & 15;    // batch-in-group (B/C col); also A-row low bits
    const int g = l >> 4;    // lane quarter
    const int batch = bb + n;
    const int len = lengths[batch];
    int lm = len;
    #pragma unroll
    for (int d = 8; d >= 1; d >>= 1) lm = max(lm, __shfl_xor(lm, d, 64));
    const int lm1 = __builtin_amdgcn_readfirstlane(lm) - 1;

    const float* fb = feat + (size_t)batch * (L_ * T_);

    // A fragments = E^T (static): A[mb][s]: row m = 16*mb + n (next tag),
    // k = 32*s + 8*g + e (prev tag). exp(trans[k][m]).
    bf16x8 Af[4][2];
    #pragma unroll
    for (int mb = 0; mb < 4; ++mb)
        #pragma unroll
        for (int s = 0; s < 2; ++s) {
            float e[8];
            #pragma unroll
            for (int ee = 0; ee < 8; ++ee)
                e[ee] = __expf(trans[(32 * s + 8 * g + ee) * TS_ + 16 * mb + n]);
            Af[mb][s] = mkfrag(cvtpk(e[0], e[1]), cvtpk(e[2], e[3]),
                               cvtpk(e[4], e[5]), cvtpk(e[6], e[7]));
        }

    // B state (P^T, bf16 pairs): bst[s][q] = tags (32s+8g+2q, +1) for batch n.
    int bst[2][4];
    #pragma unroll
    for (int s = 0; s < 2; ++s)
        #pragma unroll
        for (int q = 0; q < 4; ++q) {
            const int k0 = 32 * s + 8 * g + 2 * q;
            const float v0 = __expf(trans[START_ * TS_ + k0]     + fb[k0]);
            const float v1 = __expf(trans[START_ * TS_ + k0 + 1] + fb[k0 + 1]);
            bst[s][q] = cvtpk(v0, v1);
        }

    int   K   = 0;      // exact pow2 shifts applied to surviving state
    float srs = 1.0f;   // rescale factor for next u==0 step
    int   kk  = 0;

    // feature ring: ring[slot][mb] = feat row r at tags 16mb+4g..+3, slot=r&3.
    // Raw at load; exponentiated IN PLACE one step before consumption
    // (slot cycle mod 4: load@t==s, exp@t==s+3, consume@t==s+4 -> exactly once).
    f32x4 ring[4][4];
    #pragma unroll
    for (int tp = 1; tp <= 4; ++tp)
        #pragma unroll
        for (int mb = 0; mb < 4; ++mb)
            ring[tp & 3][mb] = *(const f32x4*)(fb + (size_t)tp * T_ + 16 * mb + 4 * g);
    // exp row 1 (consumed first at t=1)
    #pragma unroll
    for (int mb = 0; mb < 4; ++mb) {
        ring[1][mb][0] = __expf(ring[1][mb][0]); ring[1][mb][1] = __expf(ring[1][mb][1]);
        ring[1][mb][2] = __expf(ring[1][mb][2]); ring[1][mb][3] = __expf(ring[1][mb][3]);
    }

    const f32x4 zf = {0.f, 0.f, 0.f, 0.f};

    for (int tb = 1; tb <= lm1; tb += 4) {
        #pragma unroll
        for (int u = 0; u < 4; ++u) {
            const int t      = tb + u;
            const int slot_c = (1 + u) & 3;   // == t&3 : consume (exp'd row t)
            const int slot_x = (2 + u) & 3;   // == (t+1)&3 : exp row t+1

            bf16x8 B0 = mkfrag(bst[0][0], bst[0][1], bst[0][2], bst[0][3]);
            bf16x8 B1 = mkfrag(bst[1][0], bst[1][1], bst[1][2], bst[1][3]);
            f32x4 acc[4];
            #pragma unroll
            for (int mb = 0; mb < 4; ++mb) {
                acc[mb] = __builtin_amdgcn_mfma_f32_16x16x32_bf16(Af[mb][0], B0, zf, 0, 0, 0);
                acc[mb] = __builtin_amdgcn_mfma_f32_16x16x32_bf16(Af[mb][1], B1, acc[mb], 0, 0, 0);
            }

            if (u == 0) {                      // apply deferred exact rescale
                K += (t < len) ? kk : 0;
                #pragma unroll
                for (int mb = 0; mb < 4; ++mb) acc[mb] *= srs;
            }
            #pragma unroll
            for (int mb = 0; mb < 4; ++mb) acc[mb] *= ring[slot_c][mb];

            // pack fp32 acc -> bf16 pairs: w[mb][p] = tags (16mb+4g+2p, +1)
            int w[4][2];
            #pragma unroll
            for (int mb = 0; mb < 4; ++mb) {
                w[mb][0] = cvtpk(acc[mb][0], acc[mb][1]);
                w[mb][1] = cvtpk(acc[mb][2], acc[mb][3]);
            }
            // permlane choreography -> bn[s][q] = tags (32s+8g+2q, +1)
            int bn[2][4];
            #pragma unroll
            for (int s = 0; s < 2; ++s)
                #pragma unroll
                for (int p = 0; p < 2; ++p) {
                    int a = w[2 * s][p], c = w[2 * s + 1][p];
                    pl32(a, c); pl16(a, c);
                    bn[s][p] = a; bn[s][2 + p] = c;
                }
            const bool upd = (t < len);        // per-batch commit mask
            #pragma unroll
            for (int s = 0; s < 2; ++s)
                #pragma unroll
                for (int q = 0; q < 4; ++q)
                    bst[s][q] = upd ? bn[s][q] : bst[s][q];

            if (u == 3) {
                // batch-uniform representative: tag-0 P' broadcast over g
                int x = __float_as_int(acc[0][0]);
                int y = x;
                pl32(x, y);
                int xc = x;
                pl16(x, xc);
                kk  = ((x >> 23) & 255) - 127;
                srs = __int_as_float((127 - kk) << 23);   // 2^-kk
            }

            // exp row t+1 in place (loaded 3 steps ago — data resident)
            #pragma unroll
            for (int mb = 0; mb < 4; ++mb) {
                ring[slot_x][mb][0] = __expf(ring[slot_x][mb][0]);
                ring[slot_x][mb][1] = __expf(ring[slot_x][mb][1]);
                ring[slot_x][mb][2] = __expf(ring[slot_x][mb][2]);
                ring[slot_x][mb][3] = __expf(ring[slot_x][mb][3]);
            }
            // prefetch raw row t+4 into the slot just consumed
            int tl4 = t + 4; if (tl4 > L_ - 1) tl4 = L_ - 1;
            #pragma unroll
            for (int mb = 0; mb < 4; ++mb)
                ring[slot_c][mb] = *(const f32x4*)(fb + (size_t)tl4 * T_ + 16 * mb + 4 * g);
        }
    }

    // logZ = log(sum_k P_k * exp(trans[k][END])) + K*ln2
    float sum = 0.f;
    #pragma unroll
    for (int s = 0; s < 2; ++s)
        #pragma unroll
        for (int q = 0; q < 4; ++q) {
            const int k0 = 32 * s + 8 * g + 2 * q;
            const float lo = __int_as_float(bst[s][q] << 16);
            const float hi = __int_as_float(bst[s][q] & 0xffff0000);
            sum += lo * __expf(trans[k0 * TS_ + END_]);
            sum += hi * __expf(trans[(k0 + 1) * TS_ + END_]);
        }
    sum += __shfl_xor(sum, 16, 64);
    sum += __shfl_xor(sum, 32, 64);
    if (g == 0) {
        const float logZ = __logf(sum) + (float)K * LN2_;
        atomicAdd(out, logZ * (1.0f / (float)B_));
    }
}

extern "C" void kernel_launch(void* const* d_in, const int* in_sizes, int n_in,
                              void* d_out, int out_size, void* d_ws, size_t ws_size,
                              hipStream_t stream) {
    const float* features    = (const float*)d_in[0];
    const int*   tags        = (const int*)d_in[1];
    const int*   lengths     = (const int*)d_in[2];
    const float* transitions = (const float*)d_in[3];
    float* out = (float*)d_out;

    hipMemsetAsync(out, 0, sizeof(float), stream);
    crf_fused<<<B_ / NB_, 256, 0, stream>>>(features, tags, lengths, transitions, out);
}

// Round 9
// 513.888 us; speedup vs baseline: 1.8929x; 1.8929x over previous
//
#include <hip/hip_runtime.h>

#define B_ 256
#define L_ 2048
#define T_ 64
#define TS_ 66   // TRANS_SIZE
#define START_ 64
#define END_ 65
#define NB_ 16        // batches per fwd block
#define CH_ 8         // time steps per chunk
#define RSTRIDE_ 68   // floats per (row,batch) line: 17*4 -> 16B-aligned, 2-way banks (free)
#define BUFSZ_ (CH_ * 16 * RSTRIDE_)   // 8704 floats per chunk buffer
#define LN2_ 0.69314718055994531f

typedef float f32x4 __attribute__((ext_vector_type(4)));
typedef short bf16x8 __attribute__((ext_vector_type(8)));
typedef int   i32x4 __attribute__((ext_vector_type(4)));

__device__ __forceinline__ int cvtpk(float lo, float hi) {
    int r; asm("v_cvt_pk_bf16_f32 %0, %1, %2" : "=v"(r) : "v"(lo), "v"(hi)); return r;
}
__device__ __forceinline__ void pl32(int& a, int& b) {
    asm("v_permlane32_swap_b32 %0, %1" : "+v"(a), "+v"(b));
}
__device__ __forceinline__ void pl16(int& a, int& b) {
    asm("v_permlane16_swap_b32 %0, %1" : "+v"(a), "+v"(b));
}
__device__ __forceinline__ bf16x8 mkfrag(int w0, int w1, int w2, int w3) {
    i32x4 t; t[0] = w0; t[1] = w1; t[2] = w2; t[3] = w3;
    return __builtin_bit_cast(bf16x8, t);
}

// One consumer step. FC = feature register pair (fA/fB), UU = literal 0..7.
#define CSTEP(FC, UU)                                                         \
  do {                                                                        \
    const int t = tbase + (UU);                                               \
    bf16x8 B0 = mkfrag(bst[0][0], bst[0][1], bst[0][2], bst[0][3]);           \
    bf16x8 B1 = mkfrag(bst[1][0], bst[1][1], bst[1][2], bst[1][3]);           \
    f32x4 acc[4];                                                             \
    _Pragma("unroll")                                                         \
    for (int mb = 0; mb < 4; ++mb) {                                          \
      acc[mb] = __builtin_amdgcn_mfma_f32_16x16x32_bf16(Af[mb][0], B0, zf, 0, 0, 0);      \
      acc[mb] = __builtin_amdgcn_mfma_f32_16x16x32_bf16(Af[mb][1], B1, acc[mb], 0, 0, 0); \
    }                                                                         \
    if ((UU) == 0 || (UU) == 4) {  /* apply deferred exact rescale */         \
      K += (t < len) ? kk : 0;                                                \
      _Pragma("unroll")                                                       \
      for (int mb = 0; mb < 4; ++mb) acc[mb] *= srs;                          \
    }                                                                         \
    _Pragma("unroll")                                                         \
    for (int mb = 0; mb < 4; ++mb) acc[mb] *= FC[mb];                         \
    int w[4][2];                                                              \
    _Pragma("unroll")                                                         \
    for (int mb = 0; mb < 4; ++mb) {                                          \
      w[mb][0] = cvtpk(acc[mb][0], acc[mb][1]);                               \
      w[mb][1] = cvtpk(acc[mb][2], acc[mb][3]);                               \
    }                                                                         \
    int bn[2][4];                                                             \
    _Pragma("unroll")                                                         \
    for (int s = 0; s < 2; ++s) {                                             \
      _Pragma("unroll")                                                       \
      for (int p = 0; p < 2; ++p) {                                           \
        int a = w[2 * s][p], c2 = w[2 * s + 1][p];                            \
        pl32(a, c2); pl16(a, c2);                                             \
        bn[s][p] = a; bn[s][2 + p] = c2;                                      \
      }                                                                       \
    }                                                                         \
    const bool upd = (t < len);                                               \
    _Pragma("unroll")                                                         \
    for (int s = 0; s < 2; ++s) {                                             \
      _Pragma("unroll")                                                       \
      for (int q = 0; q < 4; ++q) bst[s][q] = upd ? bn[s][q] : bst[s][q];     \
    }                                                                         \
    if ((UU) == 3 || (UU) == 7) {  /* compute next rescale from this acc */   \
      int x = __float_as_int(acc[0][0]);                                      \
      int y = x; pl32(x, y);                                                  \
      int xc = x; pl16(x, xc);                                                \
      kk  = ((x >> 23) & 255) - 127;                                          \
      srs = __int_as_float((127 - kk) << 23);                                 \
    }                                                                         \
    if ((UU) < 6) {  /* refill consumed buffer with row UU+2 of this chunk */ \
      _Pragma("unroll")                                                       \
      for (int mb = 0; mb < 4; ++mb)                                          \
        FC[mb] = *(const f32x4*)(base + (((UU) + 2) * 16 + n) * RSTRIDE_ + 16 * mb + 4 * g); \
    }                                                                         \
  } while (0)

// Producer staging helpers (waves 1-3; 192 lanes handle 2048 16B-chunks).
#define P_DECODE(i)                                                           \
    const int id = plane + 192 * (i);                                         \
    const bool ok = (id < 2048);                                              \
    const int row = id >> 8, rem = id & 255, pn = rem >> 4, G = rem & 15;

#define P_LOAD(i, CC)                                                         \
  do { P_DECODE(i)                                                            \
    if (ok) {                                                                 \
      int rg = 1 + (CC) * CH_ + row; if (rg > L_ - 1) rg = L_ - 1;            \
      pv[i] = *(const f32x4*)(feat + (size_t)(bb + pn) * (L_ * T_) +          \
                              (size_t)rg * T_ + 4 * G);                       \
    }                                                                         \
  } while (0)

#define P_STORE(i, CC)                                                        \
  do { P_DECODE(i)                                                            \
    if (ok) {                                                                 \
      f32x4 v = pv[i];                                                        \
      v[0] = __expf(v[0]); v[1] = __expf(v[1]);                               \
      v[2] = __expf(v[2]); v[3] = __expf(v[3]);                               \
      *(f32x4*)(sbuf + ((CC) & 1) * BUFSZ_ +                                  \
                (row * 16 + pn) * RSTRIDE_ + 4 * G) = v;                      \
    }                                                                         \
  } while (0)

// grid = 32 blocks x 256 threads.
// Blocks 0-15: forward chains (wave 0 = MFMA consumer, waves 1-3 = LDS producers).
// Blocks 16-31: gold-path scores (concurrent on other CUs).
__global__ __launch_bounds__(256, 1) void crf_fused(
    const float* __restrict__ feat, const int* __restrict__ tags,
    const int* __restrict__ lengths, const float* __restrict__ trans,
    float* __restrict__ out)
{
    __shared__ __align__(16) float sbuf[2 * BUFSZ_];

    if (blockIdx.x >= 16) {
        // ---------------- gold-path ("real") scores, negated ----------------
        const int bb  = (blockIdx.x - 16) * NB_;
        const int wid = threadIdx.x >> 6, l = threadIdx.x & 63;
        for (int bi = wid; bi < NB_; bi += 4) {
            const int b = bb + bi;
            const int len = lengths[b];
            const int* tg = tags + (size_t)b * L_;
            const float* fbb = feat + (size_t)b * (L_ * T_);
            float local = 0.f;
            for (int t = l; t < len; t += 64)
                local += fbb[(size_t)t * T_ + tg[t]];
            for (int t = l; t + 1 < len; t += 64)
                local += trans[tg[t] * TS_ + tg[t + 1]];
            #pragma unroll
            for (int d = 32; d >= 1; d >>= 1) local += __shfl_xor(local, d, 64);
            if (l == 0) {
                local += trans[START_ * TS_ + tg[0]];
                local += trans[tg[len - 1] * TS_ + END_];
                atomicAdd(out, -local * (1.0f / (float)B_));
            }
        }
        return;
    }

    const int bb  = blockIdx.x * NB_;
    const int tid = threadIdx.x;
    const int wid = tid >> 6;
    const int l   = tid & 63;

    // block-uniform max length -> chunk count (identical in all 4 waves)
    int lm = lengths[bb + (l & 15)];
    #pragma unroll
    for (int d = 8; d >= 1; d >>= 1) lm = max(lm, __shfl_xor(lm, d, 64));
    const int lm1 = __builtin_amdgcn_readfirstlane(lm) - 1;
    const int NC  = (lm1 + CH_ - 1) / CH_;

    if (wid != 0) {
        // ---------------- producers: stage exp(features) into LDS ----------------
        const int plane = (wid - 1) * 64 + l;   // 0..191
        f32x4 pv[11];
        // prologue: chunk 0 -> buf0; then issue chunk 1 loads
        #pragma unroll
        for (int i = 0; i < 11; ++i) P_LOAD(i, 0);
        if (NC > 0) {
            #pragma unroll
            for (int i = 0; i < 11; ++i) P_STORE(i, 0);
            #pragma unroll
            for (int i = 0; i < 11; ++i) P_LOAD(i, 1);
        }
        __syncthreads();
        for (int c = 0; c < NC; ++c) {
            if (c + 1 < NC) {
                #pragma unroll
                for (int i = 0; i < 11; ++i) P_STORE(i, c + 1);
            }
            if (c + 2 < NC) {
                #pragma unroll
                for (int i = 0; i < 11; ++i) P_LOAD(i, c + 2);
            }
            __syncthreads();
        }
        return;
    }

    // ---------------- consumer: 16 MFMA chains ----------------
    const int n = l & 15;    // batch-in-group (B/C col); also A-row low bits
    const int g = l >> 4;    // lane quarter
    const int batch = bb + n;
    const int len = lengths[batch];
    const float* fb = feat + (size_t)batch * (L_ * T_);

    // A fragments = E^T (static): A[mb][s]: row m = 16*mb + n (next tag),
    // k = 32*s + 8*g + e (prev tag). exp(trans[k][m]).
    bf16x8 Af[4][2];
    #pragma unroll
    for (int mb = 0; mb < 4; ++mb)
        #pragma unroll
        for (int s = 0; s < 2; ++s) {
            float e[8];
            #pragma unroll
            for (int ee = 0; ee < 8; ++ee)
                e[ee] = __expf(trans[(32 * s + 8 * g + ee) * TS_ + 16 * mb + n]);
            Af[mb][s] = mkfrag(cvtpk(e[0], e[1]), cvtpk(e[2], e[3]),
                               cvtpk(e[4], e[5]), cvtpk(e[6], e[7]));
        }

    // B state (P^T, bf16 pairs): bst[s][q] = tags (32s+8g+2q, +1) for batch n.
    int bst[2][4];
    #pragma unroll
    for (int s = 0; s < 2; ++s)
        #pragma unroll
        for (int q = 0; q < 4; ++q) {
            const int k0 = 32 * s + 8 * g + 2 * q;
            const float v0 = __expf(trans[START_ * TS_ + k0]     + fb[k0]);
            const float v1 = __expf(trans[START_ * TS_ + k0 + 1] + fb[k0 + 1]);
            bst[s][q] = cvtpk(v0, v1);
        }

    int   K   = 0;
    float srs = 1.0f;
    int   kk  = 0;
    const f32x4 zf = {0.f, 0.f, 0.f, 0.f};

    __syncthreads();   // buf0 ready

    for (int c = 0; c < NC; ++c) {
        const float* base = sbuf + (c & 1) * BUFSZ_;
        const int tbase = 1 + c * CH_;
        f32x4 fA[4], fB[4];
        #pragma unroll
        for (int mb = 0; mb < 4; ++mb)
            fA[mb] = *(const f32x4*)(base + (0 * 16 + n) * RSTRIDE_ + 16 * mb + 4 * g);
        #pragma unroll
        for (int mb = 0; mb < 4; ++mb)
            fB[mb] = *(const f32x4*)(base + (1 * 16 + n) * RSTRIDE_ + 16 * mb + 4 * g);

        CSTEP(fA, 0); CSTEP(fB, 1); CSTEP(fA, 2); CSTEP(fB, 3);
        CSTEP(fA, 4); CSTEP(fB, 5); CSTEP(fA, 6); CSTEP(fB, 7);

        __syncthreads();
    }

    // logZ = log(sum_k P_k * exp(trans[k][END])) + K*ln2
    float sum = 0.f;
    #pragma unroll
    for (int s = 0; s < 2; ++s)
        #pragma unroll
        for (int q = 0; q < 4; ++q) {
            const int k0 = 32 * s + 8 * g + 2 * q;
            const float lo = __int_as_float(bst[s][q] << 16);
            const float hi = __int_as_float(bst[s][q] & 0xffff0000);
            sum += lo * __expf(trans[k0 * TS_ + END_]);
            sum += hi * __expf(trans[(k0 + 1) * TS_ + END_]);
        }
    sum += __shfl_xor(sum, 16, 64);
    sum += __shfl_xor(sum, 32, 64);
    if (g == 0) {
        const float logZ = __logf(sum) + (float)K * LN2_;
        atomicAdd(out, logZ * (1.0f / (float)B_));
    }
}

extern "C" void kernel_launch(void* const* d_in, const int* in_sizes, int n_in,
                              void* d_out, int out_size, void* d_ws, size_t ws_size,
                              hipStream_t stream) {
    const float* features    = (const float*)d_in[0];
    const int*   tags        = (const int*)d_in[1];
    const int*   lengths     = (const int*)d_in[2];
    const float* transitions = (const float*)d_in[3];
    float* out = (float*)d_out;

    hipMemsetAsync(out, 0, sizeof(float), stream);
    crf_fused<<<32, 256, 0, stream>>>(features, tags, lengths, transitions, out);
}

// Round 11
// 459.159 us; speedup vs baseline: 2.1185x; 1.1192x over previous
//
#include <hip/hip_runtime.h>

#define B_ 256
#define L_ 2048
#define T_ 64
#define TS_ 66   // TRANS_SIZE
#define START_ 64
#define END_ 65
#define NB_ 16        // batches per fwd block
#define CH_ 8         // time steps per chunk
#define RSTRIDE_ 68   // floats per (row,batch) line
#define BUFSZ_ (CH_ * 16 * RSTRIDE_)
#define LN2_ 0.69314718055994531f

typedef float f32x4 __attribute__((ext_vector_type(4)));
typedef short bf16x8 __attribute__((ext_vector_type(8)));
typedef int   i32x4 __attribute__((ext_vector_type(4)));

__device__ __forceinline__ int cvtpk(float lo, float hi) {
    int r; asm("v_cvt_pk_bf16_f32 %0, %1, %2" : "=v"(r) : "v"(lo), "v"(hi)); return r;
}
__device__ __forceinline__ void pl32(int& a, int& b) {
    asm("v_permlane32_swap_b32 %0, %1" : "+v"(a), "+v"(b));
}
__device__ __forceinline__ void pl16(int& a, int& b) {
    asm("v_permlane16_swap_b32 %0, %1" : "+v"(a), "+v"(b));
}
__device__ __forceinline__ bf16x8 mkfrag(int w0, int w1, int w2, int w3) {
    i32x4 t; t[0] = w0; t[1] = w1; t[2] = w2; t[3] = w3;
    return __builtin_bit_cast(bf16x8, t);
}

// One consumer step, sigma-layout (B packed directly from acc — no permlanes
// on the critical path). FC = feature reg set (fA/fB), UU literal 0..7.
#define CSTEP(FC, UU)                                                         \
  do {                                                                        \
    const int t = tbase + (UU);                                               \
    bf16x8 B0 = mkfrag(bs[0][0], bs[0][1], bs[0][2], bs[0][3]);               \
    bf16x8 B1 = mkfrag(bs[1][0], bs[1][1], bs[1][2], bs[1][3]);               \
    f32x4 acc[4];                                                             \
    _Pragma("unroll")                                                         \
    for (int mb = 0; mb < 4; ++mb) {                                          \
      acc[mb] = __builtin_amdgcn_mfma_f32_16x16x32_bf16(Af[mb][0], B0, zf, 0, 0, 0);      \
      acc[mb] = __builtin_amdgcn_mfma_f32_16x16x32_bf16(Af[mb][1], B1, acc[mb], 0, 0, 0); \
    }                                                                         \
    if ((UU) == 0 || (UU) == 4) K += (t < len) ? kk : 0;                      \
    _Pragma("unroll")                                                         \
    for (int mb = 0; mb < 4; ++mb) acc[mb] *= FC[mb];                         \
    int nw[2][4];                                                             \
    nw[0][0] = cvtpk(acc[0][0], acc[0][1]); nw[0][1] = cvtpk(acc[0][2], acc[0][3]); \
    nw[0][2] = cvtpk(acc[1][0], acc[1][1]); nw[0][3] = cvtpk(acc[1][2], acc[1][3]); \
    nw[1][0] = cvtpk(acc[2][0], acc[2][1]); nw[1][1] = cvtpk(acc[2][2], acc[2][3]); \
    nw[1][2] = cvtpk(acc[3][0], acc[3][1]); nw[1][3] = cvtpk(acc[3][2], acc[3][3]); \
    const bool upd = (t < len);                                               \
    _Pragma("unroll")                                                         \
    for (int s = 0; s < 2; ++s) {                                             \
      _Pragma("unroll")                                                       \
      for (int r = 0; r < 4; ++r) bs[s][r] = upd ? nw[s][r] : bs[s][r];       \
    }                                                                         \
    if ((UU) == 3 || (UU) == 7) {  /* next rescale from this acc (1-step slack) */ \
      int x = __float_as_int(acc[0][0]);                                      \
      int y = x; pl32(x, y);                                                  \
      int xc = x; pl16(x, xc);                                                \
      kk  = ((x >> 23) & 255) - 127;                                          \
      srs = __int_as_float((127 - kk) << 23);                                 \
      if ((UU) == 3) {  /* fold into row-4 features (held in fA) */           \
        _Pragma("unroll")                                                     \
        for (int mb = 0; mb < 4; ++mb) fA[mb] *= srs;                         \
      }                                                                       \
    }                                                                         \
    if ((UU) < 6) {                                                           \
      _Pragma("unroll")                                                       \
      for (int mb = 0; mb < 4; ++mb)                                          \
        FC[mb] = *(const f32x4*)(base + (((UU) + 2) * 16 + n) * RSTRIDE_ + 16 * mb + 4 * g); \
    }                                                                         \
  } while (0)

// Producer staging helpers (waves 1-3; 192 lanes cover 2048 16B-chunks).
#define P_DECODE(i)                                                           \
    const int id = plane + 192 * (i);                                         \
    const bool ok = (id < 2048);                                              \
    const int row = id >> 8, rem = id & 255, pn = rem >> 4, G = rem & 15;

#define P_LOAD(i, CC)                                                         \
  do { P_DECODE(i)                                                            \
    if (ok) {                                                                 \
      int rg = 1 + (CC) * CH_ + row; if (rg > L_ - 1) rg = L_ - 1;            \
      pv[i] = *(const f32x4*)(feat + (size_t)(bb + pn) * (L_ * T_) +          \
                              (size_t)rg * T_ + 4 * G);                       \
    }                                                                         \
  } while (0)

#define P_STORE(i, CC)                                                        \
  do { P_DECODE(i)                                                            \
    if (ok) {                                                                 \
      f32x4 v = pv[i];                                                        \
      v[0] = __expf(v[0]); v[1] = __expf(v[1]);                               \
      v[2] = __expf(v[2]); v[3] = __expf(v[3]);                               \
      *(f32x4*)(sbuf + ((CC) & 1) * BUFSZ_ +                                  \
                (row * 16 + pn) * RSTRIDE_ + 4 * G) = v;                      \
    }                                                                         \
  } while (0)

// grid = 32 x 256. Blocks 0-15: fwd chains (wave0 consumer, waves1-3 producers).
// Blocks 16-31: gold-path scores (separate CUs, concurrent).
__global__ __launch_bounds__(256, 1) void crf_fused(
    const float* __restrict__ feat, const int* __restrict__ tags,
    const int* __restrict__ lengths, const float* __restrict__ trans,
    float* __restrict__ out)
{
    __shared__ __align__(16) float sbuf[2 * BUFSZ_];

    if (blockIdx.x >= 16) {
        const int bb  = (blockIdx.x - 16) * NB_;
        const int wid = threadIdx.x >> 6, l = threadIdx.x & 63;
        for (int bi = wid; bi < NB_; bi += 4) {
            const int b = bb + bi;
            const int len = lengths[b];
            const int* tg = tags + (size_t)b * L_;
            const float* fbb = feat + (size_t)b * (L_ * T_);
            float local = 0.f;
            for (int t = l; t < len; t += 64)
                local += fbb[(size_t)t * T_ + tg[t]];
            for (int t = l; t + 1 < len; t += 64)
                local += trans[tg[t] * TS_ + tg[t + 1]];
            #pragma unroll
            for (int d = 32; d >= 1; d >>= 1) local += __shfl_xor(local, d, 64);
            if (l == 0) {
                local += trans[START_ * TS_ + tg[0]];
                local += trans[tg[len - 1] * TS_ + END_];
                atomicAdd(out, -local * (1.0f / (float)B_));
            }
        }
        return;
    }

    const int bb  = blockIdx.x * NB_;
    const int tid = threadIdx.x;
    const int wid = tid >> 6;
    const int l   = tid & 63;

    int lm = lengths[bb + (l & 15)];
    #pragma unroll
    for (int d = 8; d >= 1; d >>= 1) lm = max(lm, __shfl_xor(lm, d, 64));
    const int lm1 = __builtin_amdgcn_readfirstlane(lm) - 1;
    const int NC  = (lm1 + CH_ - 1) / CH_;

    if (wid != 0) {
        // ---------------- producers: stage exp(features) into LDS ----------------
        const int plane = (wid - 1) * 64 + l;   // 0..191
        f32x4 pv[11];
        #pragma unroll
        for (int i = 0; i < 11; ++i) P_LOAD(i, 0);
        if (NC > 0) {
            #pragma unroll
            for (int i = 0; i < 11; ++i) P_STORE(i, 0);
            #pragma unroll
            for (int i = 0; i < 11; ++i) P_LOAD(i, 1);
        }
        __syncthreads();
        for (int c = 0; c < NC; ++c) {
            if (c + 1 < NC) {
                #pragma unroll
                for (int i = 0; i < 11; ++i) P_STORE(i, c + 1);
            }
            if (c + 2 < NC) {
                #pragma unroll
                for (int i = 0; i < 11; ++i) P_LOAD(i, c + 2);
            }
            __syncthreads();
        }
        return;
    }

    // ---------------- consumer: 16 MFMA chains, sigma layout ----------------
    const int n = l & 15;    // batch-in-group (B/C col)
    const int g = l >> 4;    // lane quarter
    const int batch = bb + n;
    const int len = lengths[batch];
    const float* fb = feat + (size_t)batch * (L_ * T_);

    // sigma k-map: slot (g,e) of half s carries tag 32s + 16*(e>>2) + 4g + (e&3)
    // (exactly the C/D accumulator layout, so B packs straight from acc).
    bf16x8 Af[4][2];
    #pragma unroll
    for (int mb = 0; mb < 4; ++mb)
        #pragma unroll
        for (int s = 0; s < 2; ++s) {
            float e[8];
            #pragma unroll
            for (int ee = 0; ee < 8; ++ee) {
                const int ktag = 32 * s + 16 * (ee >> 2) + 4 * g + (ee & 3);
                e[ee] = __expf(trans[ktag * TS_ + 16 * mb + n]);
            }
            Af[mb][s] = mkfrag(cvtpk(e[0], e[1]), cvtpk(e[2], e[3]),
                               cvtpk(e[4], e[5]), cvtpk(e[6], e[7]));
        }

    // B state in sigma layout: bs[s][r] = tags (32s + 16*(r>>1) + 4g + 2*(r&1), +1)
    int bs[2][4];
    #pragma unroll
    for (int s = 0; s < 2; ++s)
        #pragma unroll
        for (int r = 0; r < 4; ++r) {
            const int k0 = 32 * s + 16 * (r >> 1) + 4 * g + 2 * (r & 1);
            const float v0 = __expf(trans[START_ * TS_ + k0]     + fb[k0]);
            const float v1 = __expf(trans[START_ * TS_ + k0 + 1] + fb[k0 + 1]);
            bs[s][r] = cvtpk(v0, v1);
        }

    int   K   = 0;
    float srs = 1.0f;
    int   kk  = 0;
    const f32x4 zf = {0.f, 0.f, 0.f, 0.f};

    __syncthreads();   // buf0 ready

    for (int c = 0; c < NC; ++c) {
        const float* base = sbuf + (c & 1) * BUFSZ_;
        const int tbase = 1 + c * CH_;
        f32x4 fA[4], fB[4];
        #pragma unroll
        for (int mb = 0; mb < 4; ++mb)
            fA[mb] = *(const f32x4*)(base + (0 * 16 + n) * RSTRIDE_ + 16 * mb + 4 * g);
        #pragma unroll
        for (int mb = 0; mb < 4; ++mb)
            fB[mb] = *(const f32x4*)(base + (1 * 16 + n) * RSTRIDE_ + 16 * mb + 4 * g);
        #pragma unroll
        for (int mb = 0; mb < 4; ++mb) fA[mb] *= srs;   // rescale from prev u==7

        CSTEP(fA, 0); CSTEP(fB, 1); CSTEP(fA, 2); CSTEP(fB, 3);
        CSTEP(fA, 4); CSTEP(fB, 5); CSTEP(fA, 6); CSTEP(fB, 7);

        __syncthreads();
    }

    // logZ = log(sum_k P_k * exp(trans[k][END])) + K*ln2
    float sum = 0.f;
    #pragma unroll
    for (int s = 0; s < 2; ++s)
        #pragma unroll
        for (int r = 0; r < 4; ++r) {
            const int k0 = 32 * s + 16 * (r >> 1) + 4 * g + 2 * (r & 1);
            const float lo = __int_as_float(bs[s][r] << 16);
            const float hi = __int_as_float(bs[s][r] & 0xffff0000);
            sum += lo * __expf(trans[k0 * TS_ + END_]);
            sum += hi * __expf(trans[(k0 + 1) * TS_ + END_]);
        }
    sum += __shfl_xor(sum, 16, 64);
    sum += __shfl_xor(sum, 32, 64);
    if (g == 0) {
        const float logZ = __logf(sum) + (float)K * LN2_;
        atomicAdd(out, logZ * (1.0f / (float)B_));
    }
}

extern "C" void kernel_launch(void* const* d_in, const int* in_sizes, int n_in,
                              void* d_out, int out_size, void* d_ws, size_t ws_size,
                              hipStream_t stream) {
    const float* features    = (const float*)d_in[0];
    const int*   tags        = (const int*)d_in[1];
    const int*   lengths     = (const int*)d_in[2];
    const float* transitions = (const float*)d_in[3];
    float* out = (float*)d_out;

    hipMemsetAsync(out, 0, sizeof(float), stream);
    crf_fused<<<32, 256, 0, stream>>>(features, tags, lengths, transitions, out);
}